// Round 18
// baseline (28.801 us; speedup 1.0000x reference)
//
#include <hip/hip_runtime.h>
#include <math.h>

#define NPT 512
#define BROWS 4096

typedef _Float16 half8  __attribute__((ext_vector_type(8)));
typedef _Float16 h2     __attribute__((ext_vector_type(2)));
typedef float    f32x16 __attribute__((ext_vector_type(16)));

__device__ __forceinline__ float sigmoidf_fast(float x) {
    return 1.0f / (1.0f + __expf(-x));
}

__device__ __forceinline__ h2 pkrtz(float a, float b) {
    return __builtin_bit_cast(h2, __builtin_amdgcn_cvt_pkrtz(a, b));
}

#if __has_builtin(__builtin_amdgcn_fdot2)
__device__ __forceinline__ float fdot2(h2 a, h2 b, float c) {
    return __builtin_amdgcn_fdot2(__builtin_bit_cast(__fp16 __attribute__((ext_vector_type(2))), a),
                                  __builtin_bit_cast(__fp16 __attribute__((ext_vector_type(2))), b),
                                  c, false);
}
#else
__device__ __forceinline__ float fdot2(h2 a, h2 b, float c) {
    c = fmaf((float)a[0], (float)b[0], c);
    c = fmaf((float)a[1], (float)b[1], c);
    return c;
}
#endif

union H8 { half8 v; h2 p[4]; unsigned int w[4]; };

__device__ __forceinline__ f32x16 mfma32(half8 a, half8 b, f32x16 c) {
    return __builtin_amdgcn_mfma_f32_32x32x16_f16(a, b, c, 0, 0, 0);
}

// v_permlane32_swap_b32 via inline asm: a_hi <-> b_lo. (verified rounds 12-17)
__device__ __forceinline__ void pl32swap(unsigned &a, unsigned &b) {
    asm volatile("v_permlane32_swap_b32 %0, %1" : "+v"(a), "+v"(b));
}

// Build one 16-ch-window B fragment from 4 packed row-pair words (verified).
__device__ __forceinline__ half8 makeB2(unsigned p0, unsigned p1,
                                        unsigned p2, unsigned p3) {
    pl32swap(p0, p2);
    pl32swap(p1, p3);
    H8 B; B.w[0] = p0; B.w[1] = p1; B.w[2] = p2; B.w[3] = p3;
    return B.v;
}

// Lane<->lane+32 exchange (round-17 verified): builtin if present, else shfl.
#if __has_builtin(__builtin_amdgcn_permlane32_swap)
#define HAVE_PL32_BUILTIN 1
__device__ __forceinline__ void bothT(unsigned u, unsigned &t0, unsigned &t1) {
    auto r = __builtin_amdgcn_permlane32_swap(u, u, false, false);
    t0 = r[0]; t1 = r[1];
}
#else
#define HAVE_PL32_BUILTIN 0
__device__ __forceinline__ void bothT_fallback(unsigned u, int c,
                                               unsigned &t0, unsigned &t1) {
    t0 = (unsigned)__shfl((int)u, c);
    t1 = (unsigned)__shfl((int)u, 32 + c);
}
#endif

// ---------------- single fused kernel: 1 block = 2 rows = 4 waves ----------------
// Round-17 verified math; MLP phase restructured into 3 explicit phases:
//   A: issue ALL 12 position loads (independent, one overlapped burst)
//   B: features -> 8 packed f16 words (VALU only; frees position regs)
//   C: 8 T-chains with NO global access on any chain head
__global__ __launch_bounds__(256, 4) void wps_kernel(
    const float* __restrict__ wp,    // (B, N, 2)
    const float* __restrict__ sww,
    const float* __restrict__ W1,    // (4, 64)
    const float* __restrict__ b1,    // (64,)
    const float* __restrict__ W2,    // (64, 32)
    const float* __restrict__ b2,    // (32,)
    const float* __restrict__ W3,    // (32, 1)
    const float* __restrict__ b3,    // (1,)
    float* __restrict__ out)
{
    __shared__ float sLg[2][NPT];    // raw logits, 4 KB
    __shared__ float2 sY[2];         // y_255 per row

    const int t    = threadIdx.x;
    const int lane = t & 63;
    const int wv   = t >> 6;
    const int row0 = blockIdx.x * 2;
    const int c    = lane & 31;
    const int hi   = lane >> 5;

    const int seg = wv * 128;

    // ---- Phase A: all 12 position loads, issued together ----
    float2 pC[4], pM[4], pP[4];
    #pragma unroll
    for (int q4 = 0; q4 < 4; ++q4) {
        const int r  = q4 >> 1;
        const int s2 = q4 & 1;
        const float2* P = (const float2*)(wp + (size_t)(row0 + r) * NPT * 2);
        const int g = seg + s2 * 64 + lane;
        pC[q4] = P[g];
        pM[q4] = P[(g > 0) ? g - 1 : 0];
        pP[q4] = P[(g < NPT - 1) ? g + 1 : NPT - 1];
    }

    // ---- constants built inline (round-12/13 verified mappings) ----
    half8 A1t[2];
    #pragma unroll
    for (int tt = 0; tt < 2; ++tt) {
        H8 a;
        a.w[0] = 0u; a.w[1] = 0u; a.w[2] = 0u; a.w[3] = 0u;
        if (hi == 0) {
            const int ch = tt * 32 + c;
            h2 v0; v0[0] = (_Float16)W1[0 * 64 + ch]; v0[1] = (_Float16)W1[1 * 64 + ch];
            h2 v1; v1[0] = (_Float16)W1[2 * 64 + ch]; v1[1] = (_Float16)W1[3 * 64 + ch];
            h2 v2; v2[0] = (_Float16)b1[ch];          v2[1] = (_Float16)0.f;
            a.p[0] = v0; a.p[1] = v1; a.p[2] = v2;
        }
        A1t[tt] = a.v;
    }
    half8 A2s[4];
    #pragma unroll
    for (int s = 0; s < 4; ++s) {
        H8 a;
        #pragma unroll
        for (int jj = 0; jj < 4; ++jj) {
            const int k = s * 16 + hi * 8 + 2 * jj;
            h2 v; v[0] = (_Float16)W2[k * 32 + c]; v[1] = (_Float16)W2[(k + 1) * 32 + c];
            a.p[jj] = v;
        }
        A2s[s] = a.v;
    }
    h2 b2p[8], w3p[8];
    #pragma unroll
    for (int rr = 0; rr < 8; ++rr) {
        const int q    = 2 * rr;
        const int drow = (q & 3) + 8 * (q >> 2) + 4 * hi;
        h2 bv;  bv[0]  = (_Float16)b2[drow]; bv[1]  = (_Float16)b2[drow + 1];
        h2 wv2; wv2[0] = (_Float16)W3[drow]; wv2[1] = (_Float16)W3[drow + 1];
        b2p[rr] = bv;
        w3p[rr] = wv2;
    }

    h2 zeroh; zeroh[0] = (_Float16)0.f; zeroh[1] = (_Float16)0.f;
    const f32x16 zero16 = {0.f,0.f,0.f,0.f,0.f,0.f,0.f,0.f,
                           0.f,0.f,0.f,0.f,0.f,0.f,0.f,0.f};

    // ---- Phase B: features -> packed f16 (VALU only) ----
    unsigned u01a[4], u23a[4];
    #pragma unroll
    for (int q4 = 0; q4 < 4; ++q4) {
        const int s2 = q4 & 1;
        const int g  = seg + s2 * 64 + lane;
        float d1x, d1y;
        if (g < NPT - 1) { d1x = pP[q4].x - pC[q4].x; d1y = pP[q4].y - pC[q4].y; }
        else             { d1x = pC[q4].x - pM[q4].x; d1y = pC[q4].y - pM[q4].y; }
        float d2x = 0.f, d2y = 0.f;
        if (g >= 1 && g <= NPT - 2) {
            d2x = pP[q4].x - 2.f * pC[q4].x + pM[q4].x;
            d2y = pP[q4].y - 2.f * pC[q4].y + pM[q4].y;
        }
        u01a[q4] = __builtin_bit_cast(unsigned, pkrtz(d1x, d1y));
        u23a[q4] = __builtin_bit_cast(unsigned, pkrtz(d2x, d2y));
    }

    // ---- Phase C: 8 T-chains, no global loads (round-17 verified math) ----
    #pragma unroll
    for (int q4 = 0; q4 < 4; ++q4) {
        const int r    = q4 >> 1;
        const int s2   = q4 & 1;
        const int base = seg + s2 * 64;

        unsigned f01T[2], f23T[2];
#if HAVE_PL32_BUILTIN
        bothT(u01a[q4], f01T[0], f01T[1]);
        bothT(u23a[q4], f23T[0], f23T[1]);
#else
        bothT_fallback(u01a[q4], c, f01T[0], f01T[1]);
        bothT_fallback(u23a[q4], c, f23T[0], f23T[1]);
#endif

        #pragma unroll
        for (int T = 0; T < 2; ++T) {
            // B1: k0-3 = features, k4 = 1.0 (bias), k5-7 = 0 (verified)
            H8 B1;
            B1.w[0] = f01T[T]; B1.w[1] = f23T[T];
            B1.w[2] = 0x00003C00u; B1.w[3] = 0u;

            // layer 1: 2 MFMAs -> 64 pre-act channels (bias folded)
            f32x16 pre0 = mfma32(A1t[0], B1.v, zero16);
            f32x16 pre1 = mfma32(A1t[1], B1.v, zero16);

            // relu + pack row pairs
            unsigned pw0[8], pw1[8];
            #pragma unroll
            for (int rr = 0; rr < 8; ++rr) {
                pw0[rr] = __builtin_bit_cast(unsigned,
                    __builtin_elementwise_max(pkrtz(pre0[2*rr], pre0[2*rr+1]), zeroh));
                pw1[rr] = __builtin_bit_cast(unsigned,
                    __builtin_elementwise_max(pkrtz(pre1[2*rr], pre1[2*rr+1]), zeroh));
            }

            // layer 2: two INDEPENDENT 2-deep MFMA chains (verified)
            f32x16 accA = zero16;
            f32x16 accB = zero16;
            accA = mfma32(A2s[0], makeB2(pw0[0], pw0[1], pw0[2], pw0[3]), accA);
            accB = mfma32(A2s[1], makeB2(pw0[4], pw0[5], pw0[6], pw0[7]), accB);
            accA = mfma32(A2s[2], makeB2(pw1[0], pw1[1], pw1[2], pw1[3]), accA);
            accB = mfma32(A2s[3], makeB2(pw1[4], pw1[5], pw1[6], pw1[7]), accB);

            // layer 3: +b2, relu, dot with W3; partner holds other 16 rows
            float v = 0.f;
            #pragma unroll
            for (int rr = 0; rr < 8; ++rr) {
                h2 tt2 = pkrtz(accA[2*rr] + accB[2*rr],
                               accA[2*rr+1] + accB[2*rr+1]);
                tt2 = tt2 + b2p[rr];
                tt2 = __builtin_elementwise_max(tt2, zeroh);
                v = fdot2(tt2, w3p[rr], v);
            }
            // cross-half reduce: storing lanes (<32) need v[lane+32]
#if HAVE_PL32_BUILTIN
            {
                const unsigned vb = __builtin_bit_cast(unsigned, v);
                auto rr2 = __builtin_amdgcn_permlane32_swap(vb, vb, false, false);
                v += __builtin_bit_cast(float, (unsigned)rr2[1]);
            }
#else
            v += __shfl_xor(v, 32);
#endif
            if (lane < 32) sLg[r][base + T * 32 + lane] = v;
        }
    }

    __syncthreads();

    // ---- scan: 4 waves = 2 rows x 2 half-scans with prefix fixup (verified) ----
    {
        const int rloc = wv >> 1;
        const int half = wv & 1;
        const int row  = row0 + rloc;
        const float2* P = (const float2*)(wp + (size_t)row * NPT * 2);
        const float bias3 = b3[0];
        const float swv   = sigmoidf_fast(sww[0]);

        const int base = half * 256 + lane * 4;
        float wr[4];
        *reinterpret_cast<float4*>(&wr[0]) =
            *reinterpret_cast<const float4*>(&sLg[rloc][base]);

        const float4* P4 = (const float4*)P;
        float2 pts[4];
        #pragma unroll
        for (int s = 0; s < 2; ++s) {
            float4 v = P4[base / 2 + s];
            pts[2 * s].x     = v.x; pts[2 * s].y     = v.y;
            pts[2 * s + 1].x = v.z; pts[2 * s + 1].y = v.w;
        }

        float a4[4], cx4[4], cy4[4];
        float A = 1.f, Cx = 0.f, Cy = 0.f;
        #pragma unroll
        for (int i = 0; i < 4; ++i) {
            const int g = base + i;
            float a = (g == 0) ? 0.f
                               : swv * (1.f - sigmoidf_fast(wr[i] + bias3));
            float cx = (1.f - a) * pts[i].x;
            float cy = (1.f - a) * pts[i].y;
            a4[i] = a; cx4[i] = cx; cy4[i] = cy;
            Cx = fmaf(a, Cx, cx);
            Cy = fmaf(a, Cy, cy);
            A *= a;
        }
        #pragma unroll
        for (int d = 1; d < 64; d <<= 1) {
            float Ap  = __shfl_up(A, d);
            float Cpx = __shfl_up(Cx, d);
            float Cpy = __shfl_up(Cy, d);
            if (lane >= d) {
                Cx = fmaf(A, Cpx, Cx);
                Cy = fmaf(A, Cpy, Cy);
                A *= Ap;
            }
        }
        float Aex  = __shfl_up(A, 1);
        float Cxex = __shfl_up(Cx, 1);
        float Cyex = __shfl_up(Cy, 1);

        float4* orow = (float4*)(out + (size_t)row * NPT * 2);

        if (half == 0) {
            float yx = (lane == 0) ? 0.f : Cxex;
            float yy = (lane == 0) ? 0.f : Cyex;
            float ox[4], oy[4];
            #pragma unroll
            for (int i = 0; i < 4; ++i) {
                yx = fmaf(a4[i], yx, cx4[i]);
                yy = fmaf(a4[i], yy, cy4[i]);
                ox[i] = yx; oy[i] = yy;
            }
            orow[base / 2]     = make_float4(ox[0], oy[0], ox[1], oy[1]);
            orow[base / 2 + 1] = make_float4(ox[2], oy[2], ox[3], oy[3]);
            if (lane == 63) { sY[rloc].x = yx; sY[rloc].y = yy; }
        }

        __syncthreads();

        if (half == 1) {
            const float2 y255 = sY[rloc];
            float yx = (lane == 0) ? y255.x : fmaf(Aex, y255.x, Cxex);
            float yy = (lane == 0) ? y255.y : fmaf(Aex, y255.y, Cyex);
            float ox[4], oy[4];
            #pragma unroll
            for (int i = 0; i < 4; ++i) {
                yx = fmaf(a4[i], yx, cx4[i]);
                yy = fmaf(a4[i], yy, cy4[i]);
                ox[i] = yx; oy[i] = yy;
            }
            if (lane == 63) {
                float2 pe = P[NPT - 1];
                ox[3] = pe.x; oy[3] = pe.y;
            }
            orow[base / 2]     = make_float4(ox[0], oy[0], ox[1], oy[1]);
            orow[base / 2 + 1] = make_float4(ox[2], oy[2], ox[3], oy[3]);
        }
    }
}

extern "C" void kernel_launch(void* const* d_in, const int* in_sizes, int n_in,
                              void* d_out, int out_size, void* d_ws, size_t ws_size,
                              hipStream_t stream) {
    const float* wp  = (const float*)d_in[0];
    const float* sww = (const float*)d_in[1];
    const float* W1  = (const float*)d_in[2];
    const float* b1  = (const float*)d_in[3];
    const float* W2  = (const float*)d_in[4];
    const float* b2  = (const float*)d_in[5];
    const float* W3  = (const float*)d_in[6];
    const float* b3  = (const float*)d_in[7];
    float* out = (float*)d_out;

    wps_kernel<<<BROWS / 2, 256, 0, stream>>>(wp, sww, W1, b1, W2, b2, W3, b3, out);
}

// Round 19
// 27.640 us; speedup vs baseline: 1.0420x; 1.0420x over previous
//
#include <hip/hip_runtime.h>
#include <math.h>

#define NPT 512
#define BROWS 4096

typedef _Float16 half8  __attribute__((ext_vector_type(8)));
typedef _Float16 h2     __attribute__((ext_vector_type(2)));
typedef float    f32x16 __attribute__((ext_vector_type(16)));

__device__ __forceinline__ float sigmoidf_fast(float x) {
    return 1.0f / (1.0f + __expf(-x));
}

__device__ __forceinline__ h2 pkrtz(float a, float b) {
    return __builtin_bit_cast(h2, __builtin_amdgcn_cvt_pkrtz(a, b));
}

#if __has_builtin(__builtin_amdgcn_fdot2)
__device__ __forceinline__ float fdot2(h2 a, h2 b, float c) {
    return __builtin_amdgcn_fdot2(__builtin_bit_cast(__fp16 __attribute__((ext_vector_type(2))), a),
                                  __builtin_bit_cast(__fp16 __attribute__((ext_vector_type(2))), b),
                                  c, false);
}
#else
__device__ __forceinline__ float fdot2(h2 a, h2 b, float c) {
    c = fmaf((float)a[0], (float)b[0], c);
    c = fmaf((float)a[1], (float)b[1], c);
    return c;
}
#endif

union H8 { half8 v; h2 p[4]; unsigned int w[4]; };

__device__ __forceinline__ f32x16 mfma32(half8 a, half8 b, f32x16 c) {
    return __builtin_amdgcn_mfma_f32_32x32x16_f16(a, b, c, 0, 0, 0);
}

// v_permlane32_swap_b32: a[32..63] <-> b[0..31]. (verified rounds 12/13)
__device__ __forceinline__ void pl32swap(unsigned &a, unsigned &b) {
    asm volatile("v_permlane32_swap_b32 %0, %1" : "+v"(a), "+v"(b));
}

// Build one 16-ch-window B fragment from 4 packed row-pair words (verified).
__device__ __forceinline__ half8 makeB2(unsigned p0, unsigned p1,
                                        unsigned p2, unsigned p3) {
    pl32swap(p0, p2);
    pl32swap(p1, p3);
    H8 B; B.w[0] = p0; B.w[1] = p1; B.w[2] = p2; B.w[3] = p3;
    return B.v;
}

// ---------------- single fused kernel: 1 block = 2 rows = 4 waves ----------------
// Round-13 champion (verified 27.61us, absmax 0.015625). Constants built
// inline per wave (~40 VGPR; weights 9 KB -> L2-resident). MLP on 32x32x16
// MFMA (verified layouts): L1 = 2 MFMA (bias in K), permlane repack,
// L2 = 2x2 independent MFMA chains. Scan: verified split-scan.
__global__ __launch_bounds__(256, 4) void wps_kernel(
    const float* __restrict__ wp,    // (B, N, 2)
    const float* __restrict__ sww,
    const float* __restrict__ W1,    // (4, 64)
    const float* __restrict__ b1,    // (64,)
    const float* __restrict__ W2,    // (64, 32)
    const float* __restrict__ b2,    // (32,)
    const float* __restrict__ W3,    // (32, 1)
    const float* __restrict__ b3,    // (1,)
    float* __restrict__ out)
{
    __shared__ float sLg[2][NPT];    // raw logits, 4 KB
    __shared__ float2 sY[2];         // y_255 per row

    const int t    = threadIdx.x;
    const int lane = t & 63;
    const int wv   = t >> 6;
    const int row0 = blockIdx.x * 2;
    const int c    = lane & 31;
    const int hi   = lane >> 5;

    // ---- constants built inline (round-12/13 verified mappings) ----
    half8 A1t[2];
    #pragma unroll
    for (int tt = 0; tt < 2; ++tt) {
        H8 a;
        a.w[0] = 0u; a.w[1] = 0u; a.w[2] = 0u; a.w[3] = 0u;
        if (hi == 0) {
            const int ch = tt * 32 + c;
            h2 v0; v0[0] = (_Float16)W1[0 * 64 + ch]; v0[1] = (_Float16)W1[1 * 64 + ch];
            h2 v1; v1[0] = (_Float16)W1[2 * 64 + ch]; v1[1] = (_Float16)W1[3 * 64 + ch];
            h2 v2; v2[0] = (_Float16)b1[ch];          v2[1] = (_Float16)0.f;
            a.p[0] = v0; a.p[1] = v1; a.p[2] = v2;
        }
        A1t[tt] = a.v;
    }
    half8 A2s[4];
    #pragma unroll
    for (int s = 0; s < 4; ++s) {
        H8 a;
        #pragma unroll
        for (int jj = 0; jj < 4; ++jj) {
            const int k = s * 16 + hi * 8 + 2 * jj;
            h2 v; v[0] = (_Float16)W2[k * 32 + c]; v[1] = (_Float16)W2[(k + 1) * 32 + c];
            a.p[jj] = v;
        }
        A2s[s] = a.v;
    }
    h2 b2p[8], w3p[8];
    #pragma unroll
    for (int rr = 0; rr < 8; ++rr) {
        const int q    = 2 * rr;
        const int drow = (q & 3) + 8 * (q >> 2) + 4 * hi;
        h2 bv;  bv[0]  = (_Float16)b2[drow]; bv[1]  = (_Float16)b2[drow + 1];
        h2 wv2; wv2[0] = (_Float16)W3[drow]; wv2[1] = (_Float16)W3[drow + 1];
        b2p[rr] = bv;
        w3p[rr] = wv2;
    }

    h2 zeroh; zeroh[0] = (_Float16)0.f; zeroh[1] = (_Float16)0.f;
    const f32x16 zero16 = {0.f,0.f,0.f,0.f,0.f,0.f,0.f,0.f,
                           0.f,0.f,0.f,0.f,0.f,0.f,0.f,0.f};

    const int seg = wv * 128;

    #pragma unroll
    for (int r = 0; r < 2; ++r) {
        const float2* P = (const float2*)(wp + (size_t)(row0 + r) * NPT * 2);

        #pragma unroll
        for (int s2 = 0; s2 < 2; ++s2) {
            const int base = seg + s2 * 64;
            const int g    = base + lane;

            // features for THIS lane's point, computed once (verified)
            float2 p  = P[g];
            float2 pm = P[(g > 0) ? g - 1 : 0];
            float2 pp = P[(g < NPT - 1) ? g + 1 : NPT - 1];
            float d1x, d1y;
            if (g < NPT - 1) { d1x = pp.x - p.x; d1y = pp.y - p.y; }
            else             { d1x = p.x - pm.x; d1y = p.y - pm.y; }
            float d2x = 0.f, d2y = 0.f;
            if (g >= 1 && g <= NPT - 2) {
                d2x = pp.x - 2.f * p.x + pm.x;
                d2y = pp.y - 2.f * p.y + pm.y;
            }
            const int u01 = __builtin_bit_cast(int, pkrtz(d1x, d1y));
            const int u23 = __builtin_bit_cast(int, pkrtz(d2x, d2y));

            #pragma unroll
            for (int T = 0; T < 2; ++T) {
                // features of point base + T*32 + c from its owner lane
                const unsigned r01 = (unsigned)__shfl(u01, T * 32 + c);
                const unsigned r23 = (unsigned)__shfl(u23, T * 32 + c);
                // B1: k0-3 = features, k4 = 1.0 (bias), k5-7 = 0 (verified)
                H8 B1;
                B1.w[0] = r01; B1.w[1] = r23;
                B1.w[2] = 0x00003C00u; B1.w[3] = 0u;

                // layer 1: 2 MFMAs -> 64 pre-act channels (bias folded)
                f32x16 pre0 = mfma32(A1t[0], B1.v, zero16);
                f32x16 pre1 = mfma32(A1t[1], B1.v, zero16);

                // relu + pack row pairs
                unsigned pw0[8], pw1[8];
                #pragma unroll
                for (int rr = 0; rr < 8; ++rr) {
                    pw0[rr] = __builtin_bit_cast(unsigned,
                        __builtin_elementwise_max(pkrtz(pre0[2*rr], pre0[2*rr+1]), zeroh));
                    pw1[rr] = __builtin_bit_cast(unsigned,
                        __builtin_elementwise_max(pkrtz(pre1[2*rr], pre1[2*rr+1]), zeroh));
                }

                // layer 2: two INDEPENDENT 2-deep MFMA chains (halved dep latency)
                f32x16 accA = zero16;
                f32x16 accB = zero16;
                accA = mfma32(A2s[0], makeB2(pw0[0], pw0[1], pw0[2], pw0[3]), accA);
                accB = mfma32(A2s[1], makeB2(pw0[4], pw0[5], pw0[6], pw0[7]), accB);
                accA = mfma32(A2s[2], makeB2(pw1[0], pw1[1], pw1[2], pw1[3]), accA);
                accB = mfma32(A2s[3], makeB2(pw1[4], pw1[5], pw1[6], pw1[7]), accB);

                // layer 3: +b2, relu, dot with W3; partner holds other 16 rows
                float v = 0.f;
                #pragma unroll
                for (int rr = 0; rr < 8; ++rr) {
                    h2 tt2 = pkrtz(accA[2*rr] + accB[2*rr],
                                   accA[2*rr+1] + accB[2*rr+1]);
                    tt2 = tt2 + b2p[rr];
                    tt2 = __builtin_elementwise_max(tt2, zeroh);
                    v = fdot2(tt2, w3p[rr], v);
                }
                v += __shfl_xor(v, 32);
                if (lane < 32) sLg[r][base + T * 32 + lane] = v;
            }
        }
    }

    __syncthreads();

    // ---- scan: 4 waves = 2 rows x 2 half-scans with prefix fixup (verified) ----
    {
        const int rloc = wv >> 1;
        const int half = wv & 1;
        const int row  = row0 + rloc;
        const float2* P = (const float2*)(wp + (size_t)row * NPT * 2);
        const float bias3 = b3[0];
        const float swv   = sigmoidf_fast(sww[0]);

        const int base = half * 256 + lane * 4;
        float wr[4];
        *reinterpret_cast<float4*>(&wr[0]) =
            *reinterpret_cast<const float4*>(&sLg[rloc][base]);

        const float4* P4 = (const float4*)P;
        float2 pts[4];
        #pragma unroll
        for (int s = 0; s < 2; ++s) {
            float4 v = P4[base / 2 + s];
            pts[2 * s].x     = v.x; pts[2 * s].y     = v.y;
            pts[2 * s + 1].x = v.z; pts[2 * s + 1].y = v.w;
        }

        float a4[4], cx4[4], cy4[4];
        float A = 1.f, Cx = 0.f, Cy = 0.f;
        #pragma unroll
        for (int i = 0; i < 4; ++i) {
            const int g = base + i;
            float a = (g == 0) ? 0.f
                               : swv * (1.f - sigmoidf_fast(wr[i] + bias3));
            float cx = (1.f - a) * pts[i].x;
            float cy = (1.f - a) * pts[i].y;
            a4[i] = a; cx4[i] = cx; cy4[i] = cy;
            Cx = fmaf(a, Cx, cx);
            Cy = fmaf(a, Cy, cy);
            A *= a;
        }
        #pragma unroll
        for (int d = 1; d < 64; d <<= 1) {
            float Ap  = __shfl_up(A, d);
            float Cpx = __shfl_up(Cx, d);
            float Cpy = __shfl_up(Cy, d);
            if (lane >= d) {
                Cx = fmaf(A, Cpx, Cx);
                Cy = fmaf(A, Cpy, Cy);
                A *= Ap;
            }
        }
        float Aex  = __shfl_up(A, 1);
        float Cxex = __shfl_up(Cx, 1);
        float Cyex = __shfl_up(Cy, 1);

        float4* orow = (float4*)(out + (size_t)row * NPT * 2);

        if (half == 0) {
            float yx = (lane == 0) ? 0.f : Cxex;
            float yy = (lane == 0) ? 0.f : Cyex;
            float ox[4], oy[4];
            #pragma unroll
            for (int i = 0; i < 4; ++i) {
                yx = fmaf(a4[i], yx, cx4[i]);
                yy = fmaf(a4[i], yy, cy4[i]);
                ox[i] = yx; oy[i] = yy;
            }
            orow[base / 2]     = make_float4(ox[0], oy[0], ox[1], oy[1]);
            orow[base / 2 + 1] = make_float4(ox[2], oy[2], ox[3], oy[3]);
            if (lane == 63) { sY[rloc].x = yx; sY[rloc].y = yy; }
        }

        __syncthreads();

        if (half == 1) {
            const float2 y255 = sY[rloc];
            float yx = (lane == 0) ? y255.x : fmaf(Aex, y255.x, Cxex);
            float yy = (lane == 0) ? y255.y : fmaf(Aex, y255.y, Cyex);
            float ox[4], oy[4];
            #pragma unroll
            for (int i = 0; i < 4; ++i) {
                yx = fmaf(a4[i], yx, cx4[i]);
                yy = fmaf(a4[i], yy, cy4[i]);
                ox[i] = yx; oy[i] = yy;
            }
            if (lane == 63) {
                float2 pe = P[NPT - 1];
                ox[3] = pe.x; oy[3] = pe.y;
            }
            orow[base / 2]     = make_float4(ox[0], oy[0], ox[1], oy[1]);
            orow[base / 2 + 1] = make_float4(ox[2], oy[2], ox[3], oy[3]);
        }
    }
}

extern "C" void kernel_launch(void* const* d_in, const int* in_sizes, int n_in,
                              void* d_out, int out_size, void* d_ws, size_t ws_size,
                              hipStream_t stream) {
    const float* wp  = (const float*)d_in[0];
    const float* sww = (const float*)d_in[1];
    const float* W1  = (const float*)d_in[2];
    const float* b1  = (const float*)d_in[3];
    const float* W2  = (const float*)d_in[4];
    const float* b2  = (const float*)d_in[5];
    const float* W3  = (const float*)d_in[6];
    const float* b3  = (const float*)d_in[7];
    float* out = (float*)d_out;

    wps_kernel<<<BROWS / 2, 256, 0, stream>>>(wp, sww, W1, b1, W2, b2, W3, b3, out);
}